// Round 6
// baseline (1153.292 us; speedup 1.0000x reference)
//
#include <hip/hip_runtime.h>
#include <hip/hip_bf16.h>
#include <cstdint>
#include <cstddef>

// Problem constants
#define BATCH 64
#define LSEQ 200
#define HID 256
#define NH 8
#define DH 256            // per-head dim = HID
#define HD (NH*DH)        // 2048
#define MROWS (BATCH*LSEQ)   // 12800
#define EPS 1e-5f
#define CSCALE 0.09014195f   // (1/sqrt(256)) * log2(e), folded into Q projection

typedef unsigned short ushort_t;
typedef __attribute__((ext_vector_type(8))) short bf16x8;         // MFMA A/B frag (4 VGPR)
typedef __attribute__((ext_vector_type(8))) unsigned short u16x8; // 16B of bf16
typedef __attribute__((ext_vector_type(4))) float f32x4;          // MFMA C/D frag

__device__ __forceinline__ float b2f(ushort_t u) {
    union { unsigned int i; float f; } c; c.i = ((unsigned int)u) << 16; return c.f;
}
__device__ __forceinline__ ushort_t f2b(float f) {
    __hip_bfloat16 h = __float2bfloat16(f);
    union { __hip_bfloat16 h; ushort_t u; } c; c.h = h; return c.u;
}
__device__ __forceinline__ float to_f32(float x) { return x; }
__device__ __forceinline__ float to_f32(ushort_t x) { return b2f(x); }
__device__ __forceinline__ void store_val(float* p, float v) { *p = v; }
__device__ __forceinline__ void store_val(ushort_t* p, float v) { *p = f2b(v); }

// packed bf16 max / add on 8 elements
__device__ __forceinline__ u16x8 bmax8(u16x8 a, u16x8 b) {
    union U { u16x8 v; __hip_bfloat162 h[4]; };
    U ua, ub, r; ua.v = a; ub.v = b;
    #pragma unroll
    for (int i = 0; i < 4; ++i) r.h[i] = __hmax2(ua.h[i], ub.h[i]);
    return r.v;
}
__device__ __forceinline__ u16x8 badd8(u16x8 a, u16x8 b) {
    union U { u16x8 v; __hip_bfloat162 h[4]; };
    U ua, ub, r; ua.v = a; ub.v = b;
    #pragma unroll
    for (int i = 0; i < 4; ++i) r.h[i] = __hadd2(ua.h[i], ub.h[i]);
    return r.v;
}

// async global->LDS, 16 bytes per lane (LDS dest = wave-uniform base + lane*16)
__device__ __forceinline__ void gll16(const void* g, void* l) {
    __builtin_amdgcn_global_load_lds(
        (const __attribute__((address_space(1))) unsigned int*)g,
        (__attribute__((address_space(3))) unsigned int*)l, 16, 0, 0);
}

// ================= bf16 MFMA GEMM:  C[M,N] = A[M,K] @ Bt[N,K]^T + bias =================
// 128x128 tile, BK=32, 4 waves (2x2 of 64x64), global_load_lds staging, XOR-swizzled LDS.
// OMODE: 0 = row-major [m][n]; 1 = head-major [b][h][l][d]; 2 = transposed head-major
// [b][h][d][l] (row length LSEQ=200, 8B packed stores). Modes 1/2 require N==2048.
// SCALEC: multiply (acc+bias) by CSCALE (folds softmax scale*log2e into Q projection).
template<bool RELU, int OMODE, bool SCALEC>
__global__ __launch_bounds__(256) void gemm_bt(
    const ushort_t* __restrict__ A, const ushort_t* __restrict__ Bt,
    const float* __restrict__ bias, ushort_t* __restrict__ C,
    int M, int N, int K)
{
    __shared__ ushort_t As[128 * 32];
    __shared__ ushort_t Bs[128 * 32];
    const int t = threadIdx.x;
    const int m0 = blockIdx.y * 128, n0 = blockIdx.x * 128;
    const int wave = t >> 6, lane = t & 63;
    const int l15 = lane & 15, lq = lane >> 4;
    const int wr = wave >> 1, wc = wave & 1;

    f32x4 acc[4][4];
    #pragma unroll
    for (int i = 0; i < 4; ++i)
        #pragma unroll
        for (int j = 0; j < 4; ++j) acc[i][j] = (f32x4){0.f, 0.f, 0.f, 0.f};

    for (int k0 = 0; k0 < K; k0 += 32) {
        __syncthreads();
        #pragma unroll
        for (int i = 0; i < 2; ++i) {      // stage A (2 x 16B per thread)
            int li = i * 256 + t;
            int ml = li >> 2, cp = li & 3;
            int cg = cp ^ ((ml ^ (ml >> 2)) & 3);
            gll16(A + (size_t)(m0 + ml) * K + k0 + cg * 8, &As[li * 8]);
        }
        #pragma unroll
        for (int i = 0; i < 2; ++i) {      // stage B
            int li = i * 256 + t;
            int nl = li >> 2, cp = li & 3;
            int cg = cp ^ ((nl ^ (nl >> 2)) & 3);
            gll16(Bt + (size_t)(n0 + nl) * K + k0 + cg * 8, &Bs[li * 8]);
        }
        __syncthreads();
        bf16x8 af[4], bfr[4];
        #pragma unroll
        for (int i = 0; i < 4; ++i) {
            int r = wr * 64 + i * 16 + l15;
            int pc = lq ^ ((r ^ (r >> 2)) & 3);
            af[i] = *(const bf16x8*)&As[r * 32 + pc * 8];
        }
        #pragma unroll
        for (int j = 0; j < 4; ++j) {
            int r = wc * 64 + j * 16 + l15;
            int pc = lq ^ ((r ^ (r >> 2)) & 3);
            bfr[j] = *(const bf16x8*)&Bs[r * 32 + pc * 8];
        }
        #pragma unroll
        for (int i = 0; i < 4; ++i)
            #pragma unroll
            for (int j = 0; j < 4; ++j)
                acc[i][j] = __builtin_amdgcn_mfma_f32_16x16x32_bf16(af[i], bfr[j], acc[i][j], 0, 0, 0);
    }
    // epilogue: C layout col=lane&15, row=4*quad+e
    if (OMODE == 2) {
        #pragma unroll
        for (int i = 0; i < 4; ++i) {
            int mbase = m0 + wr * 64 + i * 16 + 4 * lq;         // 4-aligned; 200%4==0
            int bb = (int)(((unsigned)mbase * 5243u) >> 20);    // mbase/200
            int ll = mbase - bb * 200;
            #pragma unroll
            for (int j = 0; j < 4; ++j) {
                int n = n0 + wc * 64 + j * 16 + l15;
                float bsv = bias[n];
                ushort4 o4;
                o4.x = f2b(acc[i][j][0] + bsv); o4.y = f2b(acc[i][j][1] + bsv);
                o4.z = f2b(acc[i][j][2] + bsv); o4.w = f2b(acc[i][j][3] + bsv);
                size_t addr = ((size_t)(bb * NH + (n >> 8)) * 256 + (n & 255)) * LSEQ + ll;
                *(ushort4*)&C[addr] = o4;
            }
        }
    } else {
        #pragma unroll
        for (int i = 0; i < 4; ++i) {
            #pragma unroll
            for (int e = 0; e < 4; ++e) {
                int m = m0 + wr * 64 + i * 16 + 4 * lq + e;
                #pragma unroll
                for (int j = 0; j < 4; ++j) {
                    int n = n0 + wc * 64 + j * 16 + l15;
                    float v = acc[i][j][e] + bias[n];
                    if (RELU) v = fmaxf(v, 0.f);
                    if (SCALEC) v *= CSCALE;
                    if (OMODE == 1) {
                        int bb = (int)(((unsigned)m * 5243u) >> 20);
                        int ll = m - bb * 200;
                        size_t addr = ((((size_t)(bb * NH + (n >> 8))) * LSEQ + ll) << 8) + (n & 255);
                        C[addr] = f2b(v);
                    } else {
                        C[(size_t)m * N + n] = f2b(v);
                    }
                }
            }
        }
    }
}

// ================= fused area-attention v17 (v16 + single-barrier pipeline) ==========
// v16 (raw-V PV via P aggregation, operand-swapped QK^T, in-register P) with:
// - Ks/Vs double-buffered (2x32KB each, 128 KB LDS; still 1 block/CU, LDS was free)
// - K running max kept in REGISTERS kr[4] (no pooled-K LDS read-back per class)
// - one barrier per class step: {issue next K loads -> compute(cur) -> stage(next) ->
//   barrier}. Safe: a wave at step s+1 staging coexists only with step-s staging
//   (the step-s barrier fences step-s compute), and writes target the buffer not read.
// - barriers 32 -> 18; load latency hides under compute; waves drift so staging VALU
//   overlaps MFMA across waves.
// Register budget: v16 = 128 arch + 64 acc; +kr[4]+kf[4] in-flight = ~224 <= 256 (512,2).
__global__ __launch_bounds__(512, 2) void attn_mfma17(
    const ushort_t* __restrict__ Q, const ushort_t* __restrict__ Khm,
    const ushort_t* __restrict__ Vt, ushort_t* __restrict__ O)  // O may alias Q
{
    const int id = blockIdx.x;
    const int xcd = id & 7, slot_ = id >> 3;    // 1024 blocks: 8 xcd x 128 slots
    const int qt = slot_ & 1;
    const int bh = ((slot_ >> 1) << 3) + xcd;   // both q-blocks of bh share an XCD
    const int b = bh >> 3, h = bh & 7;
    const int q0 = qt * 128;
    const int t = threadIdx.x;
    const int wave = t >> 6, lane = t & 63;
    const int l15 = lane & 15, lq = lane >> 4;

    __shared__ ushort_t Ks[2 * 64 * 256];  // pooled K, dbuf, chunk ^ (m&15)
    __shared__ ushort_t Vs[2 * 256 * 64];  // raw V [d][kpos], dbuf, chunk ^ (d&7)

    const ushort_t* kbh = Khm + (size_t)bh * LSEQ * DH;
    const ushort_t* vtb = Vt + (size_t)bh * DH * LSEQ;   // [d][l]
    const ushort_t* qbh = Q + ((size_t)b * LSEQ) * HD + h * DH;
    const int qrow = q0 + wave * 16 + l15;

    // Q fragments (row=lane&15, k=8*quad+j); pre-scaled by CSCALE in GEMM.
    bf16x8 qf[8];
    if (qrow < LSEQ) {
        const ushort_t* qp = qbh + (size_t)qrow * HD + 8 * lq;
        #pragma unroll
        for (int g = 0; g < 8; ++g) qf[g] = *(const bf16x8*)(qp + 32 * g);
    } else {
        bf16x8 zf = {0,0,0,0,0,0,0,0};
        #pragma unroll
        for (int g = 0; g < 8; ++g) qf[g] = zf;
    }

    f32x4 oacc[16];
    #pragma unroll
    for (int i = 0; i < 16; ++i) oacc[i] = (f32x4){0.f, 0.f, 0.f, 0.f};
    float l4[4];                           // split softmax-denominator accumulators
    #pragma unroll
    for (int e = 0; e < 4; ++e) l4[e] = 0.f;
    float carry[4];                        // Pagg spill into next tile's slots 0..3
    #pragma unroll
    for (int e = 0; e < 4; ++e) carry[e] = 0.f;

    // staging roles for 512 threads
    const int dc = t & 31, mb = t >> 5;      // K: lane->d-chunk, thread->4 m's (mb 0..15)
    const int vd = t >> 1, vh = t & 1;       // V: thread -> d row, half (4 chunks each)

    u16x8 kr[4];                             // running pooled K (register-resident)

    auto loadK = [&](u16x8* kf, int row0) {
        #pragma unroll
        for (int k4 = 0; k4 < 4; ++k4)
            kf[k4] = *(const u16x8*)(kbh + (size_t)(row0 + mb + 16 * k4) * DH + dc * 8);
    };
    auto storeK = [&](int bo, const u16x8* kf) {
        #pragma unroll
        for (int k4 = 0; k4 < 4; ++k4) {
            int m = mb + 16 * k4;
            *(u16x8*)&Ks[bo + m * 256 + ((dc ^ (m & 15)) * 8)] = kf[k4];
        }
    };
    auto loadV = [&](u16x8* vc, int s0) {
        const ushort_t* vrow = vtb + (size_t)vd * LSEQ + s0 + vh * 32;
        #pragma unroll
        for (int c2 = 0; c2 < 4; ++c2) vc[c2] = *(const u16x8*)(vrow + c2 * 8);
    };
    auto storeV = [&](int bo, const u16x8* vc) {
        #pragma unroll
        for (int cl = 0; cl < 4; ++cl) {
            const int cg = vh * 4 + cl;                    // natural chunk 0..7
            const int kc = (cg >> 2) * 4 + (cg & 1) * 2;   // sigma chunk (lo half)
            const int par4 = ((cg >> 1) & 1) * 4;
            union VH { u16x8 v; ushort4 hh[2]; } nv;
            nv.v = vc[cl];
            *(ushort4*)&Vs[bo + vd * 64 + ((kc ^ (vd & 7)) * 8) + par4] = nv.hh[0];
            *(ushort4*)&Vs[bo + vd * 64 + (((kc + 1) ^ (vd & 7)) * 8) + par4] = nv.hh[1];
        }
    };

    // shift slot axis down by 1 (T'[slot] = T[slot-1], 0 fill at slot 0)
    auto shift1 = [&](float T[4][4]) {
        float up0 = __shfl(T[0][3], (lane - 16) & 63);
        float up1 = __shfl(T[1][3], (lane - 16) & 63);
        float up2 = __shfl(T[2][3], (lane - 16) & 63);
        float up3 = __shfl(T[3][3], (lane - 16) & 63);
        #pragma unroll
        for (int ms = 0; ms < 4; ++ms) {
            T[ms][3] = T[ms][2]; T[ms][2] = T[ms][1]; T[ms][1] = T[ms][0];
        }
        T[3][0] = (lq > 0) ? up3 : up2;
        T[2][0] = (lq > 0) ? up2 : up1;
        T[1][0] = (lq > 0) ? up1 : up0;
        T[0][0] = (lq > 0) ? up0 : 0.f;
    };

    // PV over the staged V tile (buffer bo) with A-frags from float P[4][4]
    auto pv32 = [&](int bo, const float P[4][4]) {
        unsigned int w[8];
        #pragma unroll
        for (int ms = 0; ms < 4; ++ms) {
            asm("v_cvt_pk_bf16_f32 %0, %1, %2" : "=v"(w[2*ms])   : "v"(P[ms][0]), "v"(P[ms][1]));
            asm("v_cvt_pk_bf16_f32 %0, %1, %2" : "=v"(w[2*ms+1]) : "v"(P[ms][2]), "v"(P[ms][3]));
        }
        union FR { unsigned int u[4]; bf16x8 v; };
        FR f0, f1;
        f0.u[0] = w[0]; f0.u[1] = w[1]; f0.u[2] = w[2]; f0.u[3] = w[3];
        f1.u[0] = w[4]; f1.u[1] = w[5]; f1.u[2] = w[6]; f1.u[3] = w[7];
        const bf16x8 pf0 = f0.v, pf1 = f1.v;
        __builtin_amdgcn_s_setprio(1);
        #pragma unroll
        for (int dt = 0; dt < 16; ++dt) {
            const int d = dt * 16 + l15;
            const int p0 = lq ^ (d & 7);
            const int p1 = (lq + 4) ^ (d & 7);
            oacc[dt] = __builtin_amdgcn_mfma_f32_16x16x32_bf16(
                           pf0, *(const bf16x8*)&Vs[bo + d * 64 + p0 * 8], oacc[dt], 0, 0, 0);
            oacc[dt] = __builtin_amdgcn_mfma_f32_16x16x32_bf16(
                           pf1, *(const bf16x8*)&Vs[bo + d * 64 + p1 * 8], oacc[dt], 0, 0, 0);
        }
        __builtin_amdgcn_s_setprio(0);
    };

    // ---- prologue: stage tile0/class0 into buffer 0 ----
    {
        u16x8 kf[4];
        u16x8 vc[4];
        loadK(kf, 0);
        loadV(vc, 0);
        #pragma unroll
        for (int k4 = 0; k4 < 4; ++k4) kr[k4] = kf[k4];
        storeK(0, kr);
        storeV(0, vc);
    }
    __syncthreads();

    // ---- 3 tiles x 5 class steps, single barrier per step ----
    int cb = 0;                                  // current Ks buffer (byte offset / 16384)
    for (int ti = 0; ti < 3; ++ti) {
        const int st0 = ti * 64;
        const int vbo = (ti & 1) * 16384;
        // carry-in: prev tile's spill -> this tile's slots 0..3 (lq==0 lanes)
        float Pagg[4][4];
        {
            float pin0 = __shfl(carry[0], (lane + 48) & 63);
            float pin1 = __shfl(carry[1], (lane + 48) & 63);
            float pin2 = __shfl(carry[2], (lane + 48) & 63);
            float pin3 = __shfl(carry[3], (lane + 48) & 63);
            #pragma unroll
            for (int ms = 0; ms < 4; ++ms)
                #pragma unroll
                for (int e = 0; e < 4; ++e) Pagg[ms][e] = 0.f;
            if (lq == 0) {
                Pagg[0][0] = pin0; Pagg[0][1] = pin1; Pagg[0][2] = pin2; Pagg[0][3] = pin3;
            }
            #pragma unroll
            for (int e = 0; e < 4; ++e) carry[e] = 0.f;
        }
        #pragma unroll
        for (int cls = 0; cls < 5; ++cls) {
            const int kbo = cb * 16384;
            const bool lastS = (cls == 4) && (ti == 2);
            // (a) issue next step's loads (latency hides under this step's compute)
            u16x8 kf[4];
            u16x8 vc[4];
            if (cls < 4) {
                loadK(kf, st0 + cls + 1);
            } else if (!lastS) {
                loadK(kf, st0 + 64);
                loadV(vc, st0 + 64);
            }
            // (b) compute: QK^T for this class (swapped operands)
            f32x4 sacc[4];
            __builtin_amdgcn_s_setprio(1);
            #pragma unroll
            for (int ms = 0; ms < 4; ++ms) {
                f32x4 s = (f32x4){0.f, 0.f, 0.f, 0.f};
                const int row = ms * 16 + l15;
                #pragma unroll
                for (int g = 0; g < 8; ++g) {
                    const int phys = (lq + 4 * g) ^ l15;
                    s = __builtin_amdgcn_mfma_f32_16x16x32_bf16(
                            *(const bf16x8*)&Ks[kbo + row * 256 + phys * 8], qf[g], s, 0, 0, 0);
                }
                sacc[ms] = s;
            }
            __builtin_amdgcn_s_setprio(0);

            // P_c = exp2(s); accumulate Pagg += sum_{u=0..cls} shift_u(P_c)
            float Pc[4][4];
            #pragma unroll
            for (int ms = 0; ms < 4; ++ms)
                #pragma unroll
                for (int e = 0; e < 4; ++e) {
                    float pe = __builtin_exp2f(sacc[ms][e]);
                    l4[e] += pe;
                    Pc[ms][e] = pe;
                    Pagg[ms][e] += pe;
                }
            if (cls >= 1) {
                float T[4][4];
                #pragma unroll
                for (int ms = 0; ms < 4; ++ms)
                    #pragma unroll
                    for (int e = 0; e < 4; ++e) T[ms][e] = Pc[ms][e];
                #pragma unroll
                for (int u = 1; u <= 4; ++u) {
                    if (u <= cls) {
                        shift1(T);
                        #pragma unroll
                        for (int ms = 0; ms < 4; ++ms)
                            #pragma unroll
                            for (int e = 0; e < 4; ++e) Pagg[ms][e] += T[ms][e];
                    }
                }
            }
            // carry-out: spill to next tile's slot i (meaningful in lq==3 lanes)
            #pragma unroll
            for (int i = 0; i < 4; ++i)
                #pragma unroll
                for (int e = 0; e < 4; ++e)
                    if (cls >= 4 + i - e) carry[i] += Pc[3][e];

            if (cls == 4) pv32(vbo, Pagg);   // one PV over raw V for the whole tile

            // (c) stage next step's buffers
            if (cls < 4) {
                #pragma unroll
                for (int k4 = 0; k4 < 4; ++k4) kr[k4] = bmax8(kr[k4], kf[k4]);
                storeK(kbo ^ 16384, kr);
            } else if (!lastS) {
                #pragma unroll
                for (int k4 = 0; k4 < 4; ++k4) kr[k4] = kf[k4];   // reset: class 0 of next tile
                storeK(kbo ^ 16384, kr);
                storeV(vbo ^ 16384, vc);
            }
            __syncthreads();
            cb ^= 1;
        }
    }

    // ---- tail staging into buffers at +16384 (cb == 1 here) ----
    {
        // K: threads with mb<8 cover slots k8*8+mb (cls=k8, off=mb), incremental max
        if (mb < 8) {
            u16x8 krun = *(const u16x8*)(kbh + (size_t)(192 + mb) * DH + dc * 8);
            const u16x8 kz = {0,0,0,0,0,0,0,0};
            #pragma unroll
            for (int k8 = 0; k8 < 8; ++k8) {
                const bool vv = (k8 <= 4) && (mb <= 7 - k8);
                if (k8 > 0 && vv)
                    krun = bmax8(krun, *(const u16x8*)(kbh + (size_t)(192 + mb + k8) * DH + dc * 8));
                int slot = k8 * 8 + mb;
                *(u16x8*)&Ks[16384 + slot * 256 + ((dc ^ (slot & 15)) * 8)] = vv ? krun : kz;
            }
        }
        // V: window sums for c<=4, chunk 5 = raw V[192..195] (carry target), 6,7 zero
        {
            u16x8 v0 = *(const u16x8*)(vtb + (size_t)vd * LSEQ + 192);
            float f[8];
            #pragma unroll
            for (int e = 0; e < 8; ++e) f[e] = b2f(v0[e]);
            #pragma unroll
            for (int cl = 0; cl < 4; ++cl) {
                const int c = vh * 4 + cl;     // chunk c == class c (slots 8c..8c+7)
                union VH { u16x8 v; ushort4 hh[2]; } ov;
                #pragma unroll
                for (int j = 0; j < 8; ++j) ov.v[j] = 0;
                if (c <= 4) {
                    #pragma unroll
                    for (int j = 0; j < 8; ++j) {
                        if (j <= 7 - c) {
                            float acc = 0.f;
                            #pragma unroll
                            for (int u = 0; u <= 4; ++u)
                                if (u <= c) acc += f[j + u];
                            ov.v[j] = f2b(acc);
                        }
                    }
                } else if (c == 5) {
                    #pragma unroll
                    for (int j = 0; j < 4; ++j) ov.v[j] = v0[j];   // raw V[192+j]
                }
                const int kc = (c >> 2) * 4 + (c & 1) * 2;
                const int par4 = ((c >> 1) & 1) * 4;
                *(ushort4*)&Vs[16384 + vd * 64 + ((kc ^ (vd & 7)) * 8) + par4] = ov.hh[0];
                *(ushort4*)&Vs[16384 + vd * 64 + (((kc + 1) ^ (vd & 7)) * 8) + par4] = ov.hh[1];
            }
        }
        __syncthreads();

        // tail compute: QK on Ks[1], softmax + carry injection, PV on Vs[1]
        f32x4 sacc[4];
        __builtin_amdgcn_s_setprio(1);
        #pragma unroll
        for (int ms = 0; ms < 4; ++ms) {
            f32x4 s = (f32x4){0.f, 0.f, 0.f, 0.f};
            const int row = ms * 16 + l15;
            #pragma unroll
            for (int g = 0; g < 8; ++g) {
                const int phys = (lq + 4 * g) ^ l15;
                s = __builtin_amdgcn_mfma_f32_16x16x32_bf16(
                        *(const bf16x8*)&Ks[16384 + row * 256 + phys * 8], qf[g], s, 0, 0, 0);
            }
            sacc[ms] = s;
        }
        __builtin_amdgcn_s_setprio(0);

        float pullc[4];
        #pragma unroll
        for (int e = 0; e < 4; ++e) pullc[e] = __shfl(carry[e], (lane + 16) & 63);
        float Pt[4][4];
        #pragma unroll
        for (int ms = 0; ms < 4; ++ms)
            #pragma unroll
            for (int e = 0; e < 4; ++e) {
                const int slot = ms * 16 + 4 * lq + e;
                const bool inval = ((slot & 7) > 7 - (slot >> 3)) || ((slot >> 3) > 4);
                float pe = __builtin_exp2f(inval ? -1e30f : sacc[ms][e]);
                l4[e] += pe;           // carry slots are invalid -> pe==0 here
                float pfrag = pe;
                if (ms == 2 && lq == 2) pfrag = pullc[e];
                Pt[ms][e] = pfrag;
            }
        pv32(16384, Pt);
    }

    // epilogue: l for q-row l15 -> reduce over the 4 lq groups, invert, redistribute
    float l_part = (l4[0] + l4[1]) + (l4[2] + l4[3]);
    l_part += __shfl_xor(l_part, 16);
    l_part += __shfl_xor(l_part, 32);
    const float inv = 1.f / l_part;

    ushort_t* ob = O + ((size_t)b * LSEQ) * HD + h * DH;
    #pragma unroll
    for (int e = 0; e < 4; ++e) {
        const int q = q0 + wave * 16 + 4 * lq + e;
        const float linv = __shfl(inv, 4 * lq + e);
        if (q < LSEQ) {
            #pragma unroll
            for (int dt = 0; dt < 16; ++dt)
                ob[(size_t)q * HD + dt * 16 + l15] = f2b(oacc[dt][e] * linv);
        }
    }
}

// ================= residual + LayerNorm: Out = LN(bf16 X + R) =================
template<typename TR, typename TO>
__global__ __launch_bounds__(256) void residual_ln(
    const ushort_t* __restrict__ X, const TR* __restrict__ R, TO* __restrict__ Out)
{
    const int row = blockIdx.x;
    const int t = threadIdx.x;
    const size_t base = (size_t)row * HID;
    float v = b2f(X[base + t]) + to_f32(R[base + t]);
    float s = v, q = v * v;
    #pragma unroll
    for (int o = 32; o > 0; o >>= 1) {
        s += __shfl_xor(s, o, 64);
        q += __shfl_xor(q, o, 64);
    }
    __shared__ float ss[4], sq[4];
    const int wave = t >> 6, lane = t & 63;
    if (lane == 0) { ss[wave] = s; sq[wave] = q; }
    __syncthreads();
    s = ss[0] + ss[1] + ss[2] + ss[3];
    q = sq[0] + sq[1] + sq[2] + sq[3];
    float mean = s * (1.f / HID);
    float var  = q * (1.f / HID) - mean * mean;
    store_val(&Out[base + t], (v - mean) * rsqrtf(var + EPS));
}

// ================= converts =================
__global__ __launch_bounds__(256) void cvt_f32_bf16(const float* __restrict__ in,
                                                    ushort_t* __restrict__ out) {
    const int i = (blockIdx.x * 256 + threadIdx.x) * 4;
    float4 v = *(const float4*)(in + i);
    ushort4 o;
    o.x = f2b(v.x); o.y = f2b(v.y); o.z = f2b(v.z); o.w = f2b(v.w);
    *(ushort4*)(out + i) = o;
}

// W[K,N] f32 -> Wt[N,K] bf16
__global__ __launch_bounds__(256) void wtrans(const float* __restrict__ W,
                                              ushort_t* __restrict__ Wt, int K, int N) {
    __shared__ float tile[32][33];
    const int t = threadIdx.x;
    const int tx = t & 31, ty = t >> 5;
    const int n0 = blockIdx.x * 32, k0 = blockIdx.y * 32;
    #pragma unroll
    for (int s = 0; s < 4; ++s)
        tile[ty + 8 * s][tx] = W[(size_t)(k0 + ty + 8 * s) * N + n0 + tx];
    __syncthreads();
    #pragma unroll
    for (int s = 0; s < 4; ++s)
        Wt[(size_t)(n0 + ty + 8 * s) * K + k0 + tx] = f2b(tile[tx][ty + 8 * s]);
}

// ================= launch =================
extern "C" void kernel_launch(void* const* d_in, const int* in_sizes, int n_in,
                              void* d_out, int out_size, void* d_ws, size_t ws_size,
                              hipStream_t stream) {
    const float* hidden = (const float*)d_in[1];
    const float* Wq = (const float*)d_in[2];  const float* bq = (const float*)d_in[3];
    const float* Wk = (const float*)d_in[4];  const float* bk = (const float*)d_in[5];
    const float* Wv = (const float*)d_in[6];  const float* bv = (const float*)d_in[7];
    const float* Wo = (const float*)d_in[8];  const float* bo = (const float*)d_in[9];
    const float* W1 = (const float*)d_in[10]; const float* b1 = (const float*)d_in[11];
    const float* W2 = (const float*)d_in[12]; const float* b2 = (const float*)d_in[13];
    float* out = (float*)d_out;

    constexpr size_t SZ_BF   = (size_t)MROWS * HD * 2;      // 52,428,800
    constexpr size_t SZ_HBF  = (size_t)MROWS * HID * 2;     // 6,553,600
    constexpr size_t SZ_WQKV = (size_t)HID * HD * 2;        // 1,048,576
    constexpr size_t SZ_W12  = (size_t)HID * 4 * HID * 2;   // 524,288
    char* ws = (char*)d_ws;
    size_t off = 0;
    ushort_t* kb   = (ushort_t*)(ws + off); off += SZ_BF;   // K head-major [b,h][l][d]
    ushort_t* vt   = (ushort_t*)(ws + off); off += SZ_BF;   // V transposed  [b,h][d][l]
    ushort_t* qo   = (ushort_t*)(ws + off); off += SZ_BF;   // q / attn-out / ffn1
    ushort_t* hb   = (ushort_t*)(ws + off); off += SZ_HBF;  // hidden bf16
    ushort_t* at1  = (ushort_t*)(ws + off); off += SZ_HBF;
    ushort_t* at2  = (ushort_t*)(ws + off); off += SZ_HBF;
    ushort_t* proj = (ushort_t*)(ws + off); off += SZ_HBF;
    ushort_t* WtQ  = (ushort_t*)(ws + off); off += SZ_WQKV;
    ushort_t* WtK  = (ushort_t*)(ws + off); off += SZ_WQKV;
    ushort_t* WtV  = (ushort_t*)(ws + off); off += SZ_WQKV;
    ushort_t* WtO  = (ushort_t*)(ws + off); off += SZ_WQKV;
    ushort_t* Wt1  = (ushort_t*)(ws + off); off += SZ_W12;
    ushort_t* Wt2  = (ushort_t*)(ws + off); off += SZ_W12;
    if (ws_size < off) return;  // total == 188,743,680 B (same as passing R3/R5-R11)
    ushort_t* ffn1 = qo;        // alias: qo free after out-proj2

    dim3 blk(256);
    cvt_f32_bf16<<<MROWS * HID / 1024, blk, 0, stream>>>(hidden, hb);
    wtrans<<<dim3(HD / 32, HID / 32), blk, 0, stream>>>(Wq, WtQ, HID, HD);
    wtrans<<<dim3(HD / 32, HID / 32), blk, 0, stream>>>(Wk, WtK, HID, HD);
    wtrans<<<dim3(HD / 32, HID / 32), blk, 0, stream>>>(Wv, WtV, HID, HD);
    wtrans<<<dim3(HID / 32, HD / 32), blk, 0, stream>>>(Wo, WtO, HD, HID);
    wtrans<<<dim3(4 * HID / 32, HID / 32), blk, 0, stream>>>(W1, Wt1, HID, 4 * HID);
    wtrans<<<dim3(HID / 32, 4 * HID / 32), blk, 0, stream>>>(W2, Wt2, 4 * HID, HID);

    const dim3 gProj(HD / 128, MROWS / 128);
    const dim3 gOut(HID / 128, MROWS / 128);
    const dim3 gF1(4 * HID / 128, MROWS / 128);

    // K head-major; V transposed head-major (shared by both MHAs)
    gemm_bt<false, 1, false><<<gProj, blk, 0, stream>>>(hb, WtK, bk, kb, MROWS, HD, HID);
    gemm_bt<false, 2, false><<<gProj, blk, 0, stream>>>(hb, WtV, bv, vt, MROWS, HD, HID);

    // MHA1 (Q pre-scaled by CSCALE)
    gemm_bt<false, 0, true><<<gProj, blk, 0, stream>>>(hb, WtQ, bq, qo, MROWS, HD, HID);
    attn_mfma17<<<2 * BATCH * NH, 512, 0, stream>>>(qo, kb, vt, qo);
    gemm_bt<false, 0, false><<<gOut, blk, 0, stream>>>(qo, WtO, bo, proj, MROWS, HID, HD);
    residual_ln<float, ushort_t><<<MROWS, blk, 0, stream>>>(proj, hidden, at1);

    // MHA2 (q from attn1; pooled K/V rebuilt from same kb/vt)
    gemm_bt<false, 0, true><<<gProj, blk, 0, stream>>>(at1, WtQ, bq, qo, MROWS, HD, HID);
    attn_mfma17<<<2 * BATCH * NH, 512, 0, stream>>>(qo, kb, vt, qo);
    gemm_bt<false, 0, false><<<gOut, blk, 0, stream>>>(qo, WtO, bo, proj, MROWS, HID, HD);
    residual_ln<ushort_t, ushort_t><<<MROWS, blk, 0, stream>>>(proj, at1, at2);

    // FFN
    gemm_bt<true, 0, false><<<gF1, blk, 0, stream>>>(at2, Wt1, b1, ffn1, MROWS, 4 * HID, HID);
    gemm_bt<false, 0, false><<<gOut, blk, 0, stream>>>(ffn1, Wt2, b2, proj, MROWS, HID, 4 * HID);
    residual_ln<ushort_t, float><<<MROWS, blk, 0, stream>>>(proj, at2, out);
}